// Round 4
// baseline (452.915 us; speedup 1.0000x reference)
//
#include <hip/hip_runtime.h>

// MultipleMappings: out[b,s,e] = sum_d X[b,s,d] * W[lang[b],e,d], passthrough if lang<0
// B=64, S=4096, D=256, L=16. fp32 I/O, bf16 MFMA compute.
// Round 6: round-5 structure + 3-deep A-chunk ring with prefetch distance 2.
//   - Round-5 post-mortem: main kernel ~155us (3.5 TB/s) vs 85us floor. Double
//     buffering gives only ONE iteration of prefetch lead (~0.3us compute) vs
//     ~2us chunk service + HBM latency jitter -> every stall lands on the
//     critical path (measured ~7us/iter vs 2us service).
//   - Fix: ring of 3 x 16 KiB A chunks, issue chunk k+2 before waiting chunk k
//     (s_waitcnt vmcnt(8)): 2 iterations of lead, 48 KiB/block in flight.
//   - Barrier audit: only buf0 is ever rewritten (chunk 3 at kc=1), so only
//     kc=0 needs a trailing barrier; 5 barriers total instead of 8.
//   - W read directly from global in fragment-major bf16 (L2-resident 2 MiB);
//     LDS = 48 KiB -> 3 blocks/CU (12 waves).

typedef __attribute__((ext_vector_type(8))) short bf16x8;
typedef __attribute__((ext_vector_type(16))) float f32x16;
typedef __attribute__((ext_vector_type(4))) float f32x4;

#define S_DIM 4096
#define D_DIM 256
#define BM 64
#define BK 64
#define NT 256

// pack two fp32 -> two bf16 (lo in low half), round-to-nearest-even
static __device__ __forceinline__ unsigned int pack_bf2(float lo, float hi) {
    unsigned int a = __float_as_uint(lo), b = __float_as_uint(hi);
    a += 0x7fffu + ((a >> 16) & 1u);
    b += 0x7fffu + ((b >> 16) & 1u);
    return (a >> 16) | (b & 0xffff0000u);
}

// 16-byte global -> LDS DMA. Dest is wave-uniform base + lane*16 (slot-ordered).
static __device__ __forceinline__ void dma16(const void* g, void* l) {
    __builtin_amdgcn_global_load_lds(
        (const __attribute__((address_space(1))) unsigned int*)g,
        (__attribute__((address_space(3))) unsigned int*)l, 16, 0, 0);
}

// W fp32 [L][256 e][256 d] -> fragment-major bf16 Wb: [L][cg(8)][k16(16)][lane(64)][8]
// lane = khalf*32 + lrow holds W[cg*32 + lrow][k16*16 + khalf*8 + j], j=0..7
// (exact mfma_f32_32x32x16_bf16 B-operand layout).
__global__ void cvt_w_kernel(const float* __restrict__ w, unsigned short* __restrict__ wb) {
    int t = blockIdx.x * NT + threadIdx.x;        // 131072 threads, one fragment slot each
    int lane = t & 63;
    int k16  = (t >> 6) & 15;
    int cg   = (t >> 10) & 7;
    int lang = t >> 13;
    int lrow = lane & 31, khalf = lane >> 5;
    const float* src = w + (((size_t)(lang << 8) + (cg << 5) + lrow) << 8) + (k16 << 4) + (khalf << 3);
    f32x4 v0 = *(const f32x4*)src;
    f32x4 v1 = *(const f32x4*)(src + 4);
    union { bf16x8 v; unsigned int u[4]; } p;
    p.u[0] = pack_bf2(v0.x, v0.y);
    p.u[1] = pack_bf2(v0.z, v0.w);
    p.u[2] = pack_bf2(v1.x, v1.y);
    p.u[3] = pack_bf2(v1.z, v1.w);
    *(bf16x8*)(wb + (size_t)t * 8) = p.v;
}

__global__ __launch_bounds__(NT, 3) void MultipleMappings_5952824672291_kernel(
    const float* __restrict__ X, const unsigned short* __restrict__ Wb,
    const int* __restrict__ pair_id, float* __restrict__ Y)
{
    // ldsA swizzle (byte offsets): (row, kg) -> row*256 + ((kg ^ (row&15)) * 16),
    // kg in [0,16) (4 fp32/group). DMA dest is linear slot*16; source is
    // inverse-swizzled (same involution). Ring of 3 x 16 KiB chunks.
    __shared__ float ldsA[3][BM * BK];

    const int b = blockIdx.y;
    const int t = threadIdx.x;
    const long base = ((long)b * S_DIM + (long)blockIdx.x * BM) * D_DIM;
    const float* Xb = X + base;
    float* Yb = Y + base;
    const int lang = pair_id[b];

    if (lang < 0) {
        // passthrough: copy 64x256 fp32 tile
        #pragma unroll
        for (int i = 0; i < 16; ++i) {
            int f4 = t + i * NT;
            f32x4 v = *(const f32x4*)(Xb + (long)f4 * 4);
            __builtin_nontemporal_store(v, (f32x4*)(Yb + (long)f4 * 4));
        }
        return;
    }

    const int lane  = t & 63;
    const int wave  = t >> 6;      // 4 waves: wave owns cols [wave*64, wave*64+64)
    const int lrow  = lane & 31;
    const int khalf = lane >> 5;   // operand k = k16*16 + khalf*8 + j

    // B fragment streams for this wave's two 32-col tiles (cg = wave*2 + ct).
    const unsigned short* wl  = Wb + (size_t)lang * (8 * 16 * 64 * 8);
    const unsigned short* wt0 = wl + (size_t)(wave * 2 + 0) * (16 * 512) + lane * 8;
    const unsigned short* wt1 = wl + (size_t)(wave * 2 + 1) * (16 * 512) + lane * 8;

    f32x16 acc00 = {}, acc01 = {}, acc10 = {}, acc11 = {};

    // A chunk stage: 64 rows x 64 d fp32 = 1024 16B slots; 4 DMA issues/thread.
    auto stage = [&](int buf, int kc) {
        #pragma unroll
        for (int j = 0; j < 4; ++j) {
            int slot = j * NT + t;
            int row = slot >> 4, kgl = slot & 15;
            int kgs = kgl ^ (row & 15);
            dma16(Xb + row * D_DIM + kc * BK + kgs * 4,
                  (char*)ldsA[buf] + slot * 16);
        }
    };

    // One K-chunk of compute from buffer `Ab` covering k16 = k16b..k16b+3.
    auto comp = [&](const char* Ab, int k16b) {
        #pragma unroll
        for (int kl = 0; kl < 4; ++kl) {
            const int k16 = k16b + kl;
            bf16x8 b0 = *(const bf16x8*)(wt0 + (size_t)k16 * 512);
            bf16x8 b1 = *(const bf16x8*)(wt1 + (size_t)k16 * 512);
            const int g0 = kl * 4 + khalf * 2;
            {
                const int row = lrow, m = row & 15;
                f32x4 a0 = *(const f32x4*)(Ab + row * 256 + ((g0 ^ m) * 16));
                f32x4 a1 = *(const f32x4*)(Ab + row * 256 + (((g0 + 1) ^ m) * 16));
                union { bf16x8 v; unsigned int u[4]; } af;
                af.u[0] = pack_bf2(a0.x, a0.y);
                af.u[1] = pack_bf2(a0.z, a0.w);
                af.u[2] = pack_bf2(a1.x, a1.y);
                af.u[3] = pack_bf2(a1.z, a1.w);
                acc00 = __builtin_amdgcn_mfma_f32_32x32x16_bf16(af.v, b0, acc00, 0, 0, 0);
                acc01 = __builtin_amdgcn_mfma_f32_32x32x16_bf16(af.v, b1, acc01, 0, 0, 0);
            }
            {
                const int row = 32 + lrow, m = row & 15;
                f32x4 a0 = *(const f32x4*)(Ab + row * 256 + ((g0 ^ m) * 16));
                f32x4 a1 = *(const f32x4*)(Ab + row * 256 + (((g0 + 1) ^ m) * 16));
                union { bf16x8 v; unsigned int u[4]; } af;
                af.u[0] = pack_bf2(a0.x, a0.y);
                af.u[1] = pack_bf2(a0.z, a0.w);
                af.u[2] = pack_bf2(a1.x, a1.y);
                af.u[3] = pack_bf2(a1.z, a1.w);
                acc10 = __builtin_amdgcn_mfma_f32_32x32x16_bf16(af.v, b0, acc10, 0, 0, 0);
                acc11 = __builtin_amdgcn_mfma_f32_32x32x16_bf16(af.v, b1, acc11, 0, 0, 0);
            }
        }
    };

    // Ring-3, prefetch distance 2. Chunk c lives in buf c%3.
    stage(0, 0);
    stage(1, 1);

    // kc=0: issue chunk2; wait chunk0 (outstanding 0,1,2 = 12 -> vmcnt(8))
    stage(2, 2);
    asm volatile("s_waitcnt vmcnt(8)" ::: "memory");
    __builtin_amdgcn_s_barrier();
    comp((const char*)ldsA[0], 0);
    __builtin_amdgcn_s_barrier();     // buf0 rewritten next -> all waves must be done

    // kc=1: issue chunk3 into buf0; wait chunk1 (outstanding 1,2,3 -> vmcnt(8))
    stage(0, 3);
    asm volatile("s_waitcnt vmcnt(8)" ::: "memory");
    __builtin_amdgcn_s_barrier();
    comp((const char*)ldsA[1], 4);

    // kc=2: wait chunk2 (outstanding 2,3 -> vmcnt(4)); buf1/buf2 never rewritten
    asm volatile("s_waitcnt vmcnt(4)" ::: "memory");
    __builtin_amdgcn_s_barrier();
    comp((const char*)ldsA[2], 8);

    // kc=3: wait chunk3 (vmcnt(0))
    asm volatile("s_waitcnt vmcnt(0)" ::: "memory");
    __builtin_amdgcn_s_barrier();
    comp((const char*)ldsA[0], 12);

    // C/D layout: col = lane&31, row = (reg&3) + 8*(reg>>2) + 4*khalf  [m74/m101]
    #pragma unroll
    for (int r = 0; r < 16; ++r) {
        const int rowg = 4 * khalf + (r & 3) + 8 * (r >> 2);
        float* y0 = Yb + (long)rowg * D_DIM + wave * 64 + lrow;
        float* y1 = y0 + 32 * D_DIM;
        __builtin_nontemporal_store(acc00[r], y0);
        __builtin_nontemporal_store(acc01[r], y0 + 32);
        __builtin_nontemporal_store(acc10[r], y1);
        __builtin_nontemporal_store(acc11[r], y1 + 32);
    }
}

extern "C" void kernel_launch(void* const* d_in, const int* in_sizes, int n_in,
                              void* d_out, int out_size, void* d_ws, size_t ws_size,
                              hipStream_t stream) {
    const float* X   = (const float*)d_in[0];   // right_emb (64,4096,256) fp32
    const float* W   = (const float*)d_in[1];   // mapping (16,256,256) fp32
    const int*   pid = (const int*)d_in[2];     // pair_id (64,1) int32
    float*       Y   = (float*)d_out;
    unsigned short* Wbf = (unsigned short*)d_ws;  // 2 MiB fragment-major bf16 W

    cvt_w_kernel<<<dim3(512), dim3(NT), 0, stream>>>(W, Wbf);

    dim3 grid(S_DIM / BM, 64);   // (64, 64) = 4096 blocks, 16/CU
    MultipleMappings_5952824672291_kernel<<<grid, dim3(NT), 0, stream>>>(X, Wbf, pid, Y);
}